// Round 1
// baseline (390.632 us; speedup 1.0000x reference)
//
#include <hip/hip_runtime.h>

#define S_LEN  4096
#define DMODEL 512
#define NH     8
#define HD     64

typedef _Float16 f16x8 __attribute__((ext_vector_type(8)));
typedef _Float16 f16x4 __attribute__((ext_vector_type(4)));
typedef float    f32x4 __attribute__((ext_vector_type(4)));

static __device__ __forceinline__ unsigned short f2h(float x) {
  return __builtin_bit_cast(unsigned short, (_Float16)x);
}

// ---------------------------------------------------------------------------
// Weight transpose + fp32->fp16: Wt[n][k] = (fp16) W[k][n].  For z==3 (Wo)
// also emits the straight fp16 copy Wof[k][n].  grid (8,8,4) block 256
// ---------------------------------------------------------------------------
__global__ __launch_bounds__(256) void wtrans_kernel(
    const float* __restrict__ w0, const float* __restrict__ w1,
    const float* __restrict__ w2, const float* __restrict__ w3,
    unsigned short* __restrict__ o0, unsigned short* __restrict__ o1,
    unsigned short* __restrict__ o2, unsigned short* __restrict__ o3,
    unsigned short* __restrict__ o3s)
{
  __shared__ unsigned short T[64 * 72];   // T[n_local][k_local], pad 72
  const float* W; unsigned short* O;
  switch (blockIdx.z) {
    case 0:  W = w0; O = o0; break;
    case 1:  W = w1; O = o1; break;
    case 2:  W = w2; O = o2; break;
    default: W = w3; O = o3; break;
  }
  const int tid = threadIdx.x;
  const int k0 = blockIdx.x * 64, n0 = blockIdx.y * 64;
  const int c4 = (tid & 15) * 4;
#pragma unroll
  for (int rp = 0; rp < 4; ++rp) {
    int r = rp * 16 + (tid >> 4);
    float4 x = *(const float4*)(W + (k0 + r) * DMODEL + n0 + c4);
    T[(c4 + 0) * 72 + r] = f2h(x.x);
    T[(c4 + 1) * 72 + r] = f2h(x.y);
    T[(c4 + 2) * 72 + r] = f2h(x.z);
    T[(c4 + 3) * 72 + r] = f2h(x.w);
    if (blockIdx.z == 3) {
      f16x4 st;
      st[0] = (_Float16)x.x; st[1] = (_Float16)x.y;
      st[2] = (_Float16)x.z; st[3] = (_Float16)x.w;
      *(f16x4*)&o3s[(k0 + r) * DMODEL + n0 + c4] = st;
    }
  }
  __syncthreads();
#pragma unroll
  for (int it = 0; it < 2; ++it) {
    int i = tid + it * 256;
    int nl = i >> 3, c = i & 7;
    *(f16x8*)&O[(n0 + nl) * DMODEL + k0 + c * 8] = *(const f16x8*)&T[nl * 72 + c * 8];
  }
}

// ---------------------------------------------------------------------------
// GEMM (multi-op): blockIdx.z selects (A,Bt,C). Body = round-2-proven kernel.
// z==3 limited to 8 M-tiles (M=512); idle z==3 blocks compute bo2.
// vtg!=null && z==2: C stored transposed (V^T). grid (64,8,nz) block 256.
// ---------------------------------------------------------------------------
__global__ __launch_bounds__(256) void gemm_kernel(
    const void* __restrict__ A0, const void* __restrict__ A1,
    const void* __restrict__ A2, const void* __restrict__ A3,
    const unsigned short* __restrict__ B0, const unsigned short* __restrict__ B1,
    const unsigned short* __restrict__ B2, const unsigned short* __restrict__ B3,
    void* __restrict__ C0, void* __restrict__ C1,
    void* __restrict__ C2, void* __restrict__ C3,
    const float* __restrict__ bias, unsigned short* __restrict__ vtg,
    const float* __restrict__ wo_f32, const float* __restrict__ bo_in,
    float* __restrict__ bo2_out,
    int a_fp32_mask, int c_fp32_mask)
{
  constexpr int K = DMODEL, N = DMODEL;
  __shared__ unsigned short As[64 * 32];
  __shared__ unsigned short Bs[64 * 32];
  const int z = blockIdx.z;
  if (z == 3 && blockIdx.x >= 8) {          // idle tiles: bo2 side-job
    if (blockIdx.x < 16 && blockIdx.y == 0 && wo_f32) {
      int col = (blockIdx.x - 8) * 64 + (threadIdx.x & 63);
      float s = bo_in[col];
#pragma unroll 8
      for (int j = 0; j < DMODEL; ++j) s = fmaf(bo_in[j], wo_f32[j * DMODEL + col], s);
      bo2_out[col] = s;
    }
    return;
  }
  const void* Av; const unsigned short* Bt; void* Cv;
  switch (z) {
    case 0:  Av = A0; Bt = B0; Cv = C0; break;
    case 1:  Av = A1; Bt = B1; Cv = C1; break;
    case 2:  Av = A2; Bt = B2; Cv = C2; break;
    default: Av = A3; Bt = B3; Cv = C3; break;
  }
  const int a_fp32 = (a_fp32_mask >> z) & 1;
  const int c_fp32 = (c_fp32_mask >> z) & 1;
  const int tid  = threadIdx.x;
  const int lane = tid & 63;
  const int wid  = tid >> 6;
  const int quad = lane >> 4, l16 = lane & 15;
  const int m0 = blockIdx.x * 64, n0 = blockIdx.y * 64;
  const int wm = (wid >> 1) * 32, wn = (wid & 1) * 32;
  const int r  = tid >> 2, ck = (tid & 3) * 8;   // staging: row, k-offset
  f32x4 acc[2][2] = {};

  for (int k0 = 0; k0 < K; k0 += 32) {
    __syncthreads();
    if (a_fp32) {
      const float* p = (const float*)Av + (m0 + r) * K + k0 + ck;
      float4 x = *(const float4*)p;
      float4 y = *(const float4*)(p + 4);
      f16x8 av;
      av[0] = (_Float16)x.x; av[1] = (_Float16)x.y;
      av[2] = (_Float16)x.z; av[3] = (_Float16)x.w;
      av[4] = (_Float16)y.x; av[5] = (_Float16)y.y;
      av[6] = (_Float16)y.z; av[7] = (_Float16)y.w;
      *(f16x8*)&As[r * 32 + ck] = av;
    } else {
      *(f16x8*)&As[r * 32 + ck] =
          *(const f16x8*)((const unsigned short*)Av + (m0 + r) * K + k0 + ck);
    }
    *(f16x8*)&Bs[r * 32 + ck] = *(const f16x8*)(Bt + (n0 + r) * K + k0 + ck);
    __syncthreads();

    f16x8 a0 = *(const f16x8*)&As[(wm + l16) * 32 + quad * 8];
    f16x8 a1 = *(const f16x8*)&As[(wm + 16 + l16) * 32 + quad * 8];
    f16x8 b0 = *(const f16x8*)&Bs[(wn + l16) * 32 + quad * 8];
    f16x8 b1 = *(const f16x8*)&Bs[(wn + 16 + l16) * 32 + quad * 8];
    acc[0][0] = __builtin_amdgcn_mfma_f32_16x16x32_f16(a0, b0, acc[0][0], 0, 0, 0);
    acc[0][1] = __builtin_amdgcn_mfma_f32_16x16x32_f16(a0, b1, acc[0][1], 0, 0, 0);
    acc[1][0] = __builtin_amdgcn_mfma_f32_16x16x32_f16(a1, b0, acc[1][0], 0, 0, 0);
    acc[1][1] = __builtin_amdgcn_mfma_f32_16x16x32_f16(a1, b1, acc[1][1], 0, 0, 0);
  }

  const int do_vt = (vtg != nullptr) && (z == 2);
#pragma unroll
  for (int mt = 0; mt < 2; ++mt)
#pragma unroll
    for (int nt = 0; nt < 2; ++nt) {
      int col = n0 + wn + nt * 16 + l16;
      float bv = bias ? bias[col] : 0.f;
#pragma unroll
      for (int g = 0; g < 4; ++g) {
        int row = m0 + wm + mt * 16 + quad * 4 + g;   // C/D: row = quad*4+reg
        float val = acc[mt][nt][g] + bv;
        if (do_vt)        vtg[col * S_LEN + row] = f2h(val);      // V^T[d][key]
        else if (c_fp32)  ((float*)Cv)[row * N + col] = val;
        else              ((unsigned short*)Cv)[row * N + col] = f2h(val);
      }
    }
}

// ---------------------------------------------------------------------------
// Split-K MFMA flash attention, S^T formulation, 2 q-sets per wave.
// Round-update: 8-wave blocks (512 thr) = 2 q-pairs x 4 key-quarters, so
// 2 blocks/CU x 8 waves = 16 waves/CU (was 8) -- kernel was latency-bound
// (Occupancy 18%, no pipe >55%). Vt stored XOR-swizzled (u = d*16 +
// (kg ^ (d&15)), kg = key-local/4): conflict-free ds_read_b64 in PV
// (pad-72 layout left half the banks idle -> the 6.4M conflict cycles).
// Ks keeps pad 72 (b128 r/w already at 2-access/bank minimum).
// Defer-max (THR=8 raw): skip alpha/rescale when tile max doesn't grow.
// 4-way kh merge via LDS scratch aliased onto Ks. grid (64, 8).
// ---------------------------------------------------------------------------
__global__ __launch_bounds__(512, 4) void attn_kernel(
    const unsigned short* __restrict__ Qb, const unsigned short* __restrict__ Kb,
    const unsigned short* __restrict__ VtG, unsigned short* __restrict__ Ob)
{
  __shared__ unsigned short Ks[4][64 * 72];   // K[n][k] per quarter, pad 72
  __shared__ unsigned short Vt[4 * 64 * 64];  // V^T swizzled, stride 64, no pad
  __shared__ float Msc[3][2][2][16];          // merge scratch m [ki][qp][s][l16]
  __shared__ float Lsc[3][2][2][16];          // merge scratch l

  const int tid  = threadIdx.x;
  const int lane = tid & 63;
  const int wid  = tid >> 6;        // 0..7
  const int qp   = wid & 1;         // q-pair (32 q-rows)
  const int kh   = wid >> 1;        // key quarter 0..3
  const int quad = lane >> 4, l16 = lane & 15;
  const int qb = blockIdx.x, h = blockIdx.y;
  const int hc = h * HD;
  const int qbase = qb * 64 + qp * 32;

  // Persistent Q fragments (B operand), 2 sets: Q[q=l16][d=quad*8+j (+32)]
  f16x8 bq[2][2];
#pragma unroll
  for (int s = 0; s < 2; ++s) {
    int qrow = qbase + s * 16 + l16;
    bq[s][0] = *(const f16x8*)(Qb + qrow * DMODEL + hc + quad * 8);
    bq[s][1] = *(const f16x8*)(Qb + qrow * DMODEL + hc + 32 + quad * 8);
  }

  // o[s][nt] holds O[q = quad*4+g][d = nt*16 + l16] for set s
  f32x4 o[2][4] = {};
  float m_run[2] = {-1e30f, -1e30f}, l_run[2] = {0.f, 0.f};

  // staging decomposition (512 threads, 2048 chunks per array):
  // it in 0..3: s = it*512+tid; sub = s>>9; n = (s>>3)&63; c = s&7
  // key quarter `sub` covers global keys sub*1024 + kb .. +63
  f16x8 kreg[4], vreg[4];
#pragma unroll
  for (int it = 0; it < 4; ++it) {     // prefetch kb = 0
    int s = it * 512 + tid;
    int sub = s >> 9, n = (s >> 3) & 63, c = s & 7;
    kreg[it] = *(const f16x8*)(Kb + (sub * 1024 + n) * DMODEL + hc + c * 8);
    vreg[it] = *(const f16x8*)(VtG + (hc + n) * S_LEN + sub * 1024 + c * 8);
  }

  for (int kbi = 0; kbi < 16; ++kbi) {
    __syncthreads();                   // all waves done reading previous tiles
#pragma unroll
    for (int it = 0; it < 4; ++it) {
      int s = it * 512 + tid;
      int sub = s >> 9, n = (s >> 3) & 63, c = s & 7;
      *(f16x8*)&Ks[sub][n * 72 + c * 8] = kreg[it];
      // swizzled Vt: element [d=n][k=8c+4*j2+jj] at u=(sub*64+n)*16+((2c+j2)^(n&15))
      int vbase = (sub * 64 + n) * 16;
      int n15 = n & 15;
      f16x4 lo = __builtin_shufflevector(vreg[it], vreg[it], 0, 1, 2, 3);
      f16x4 hi = __builtin_shufflevector(vreg[it], vreg[it], 4, 5, 6, 7);
      *(f16x4*)&Vt[(vbase + ((2 * c) ^ n15)) * 4]     = lo;
      *(f16x4*)&Vt[(vbase + ((2 * c + 1) ^ n15)) * 4] = hi;
    }
    __syncthreads();                   // staging visible

    if (kbi + 1 < 16) {                // prefetch next chunk into registers
      int kb1 = (kbi + 1) * 64;
#pragma unroll
      for (int it = 0; it < 4; ++it) {
        int s = it * 512 + tid;
        int sub = s >> 9, n = (s >> 3) & 63, c = s & 7;
        kreg[it] = *(const f16x8*)(Kb + (sub * 1024 + kb1 + n) * DMODEL + hc + c * 8);
        vreg[it] = *(const f16x8*)(VtG + (hc + n) * S_LEN + sub * 1024 + kb1 + c * 8);
      }
    }

    // ---- S^T = K Q^T : one Ks read feeds both q-sets
    f32x4 sT[2][4];
#pragma unroll
    for (int kt = 0; kt < 4; ++kt) {
      f16x8 ak0 = *(const f16x8*)&Ks[kh][(kt * 16 + l16) * 72 + quad * 8];
      f16x8 ak1 = *(const f16x8*)&Ks[kh][(kt * 16 + l16) * 72 + 32 + quad * 8];
#pragma unroll
      for (int s = 0; s < 2; ++s) {
        f32x4 a = {};
        a = __builtin_amdgcn_mfma_f32_16x16x32_f16(ak0, bq[s][0], a, 0, 0, 0);
        a = __builtin_amdgcn_mfma_f32_16x16x32_f16(ak1, bq[s][1], a, 0, 0, 0);
        sT[s][kt] = a;
      }
    }

    // ---- online softmax per set (scale 1/8 folded into exp), defer-max
    f16x4 pa[2][4];
#pragma unroll
    for (int s = 0; s < 2; ++s) {
      float vmax = -1e30f;
#pragma unroll
      for (int kt = 0; kt < 4; ++kt)
#pragma unroll
        for (int g = 0; g < 4; ++g) vmax = fmaxf(vmax, sT[s][kt][g]);
      vmax = fmaxf(vmax, __shfl_xor(vmax, 16));
      vmax = fmaxf(vmax, __shfl_xor(vmax, 32));

      if (__all(vmax <= m_run[s] + 8.0f)) {
        // deferred: keep old max, no rescale; p bounded by e^1
        const float mn = m_run[s];
        float rs = 0.f;
#pragma unroll
        for (int kt = 0; kt < 4; ++kt)
#pragma unroll
          for (int g = 0; g < 4; ++g) {
            float p = __expf((sT[s][kt][g] - mn) * 0.125f);
            rs += p;
            pa[s][kt][g] = (_Float16)p;
          }
        rs += __shfl_xor(rs, 16);
        rs += __shfl_xor(rs, 32);
        l_run[s] += rs;
      } else {
        const float mn = fmaxf(m_run[s], vmax);
        const float alpha = __expf((m_run[s] - mn) * 0.125f);
        m_run[s] = mn;

        float rs = 0.f;
#pragma unroll
        for (int kt = 0; kt < 4; ++kt)
#pragma unroll
          for (int g = 0; g < 4; ++g) {
            float p = __expf((sT[s][kt][g] - mn) * 0.125f);
            rs += p;
            pa[s][kt][g] = (_Float16)p;
          }
        rs += __shfl_xor(rs, 16);
        rs += __shfl_xor(rs, 32);
        l_run[s] = l_run[s] * alpha + rs;

        float ag[4];
#pragma unroll
        for (int g = 0; g < 4; ++g) ag[g] = __shfl(alpha, quad * 4 + g);
#pragma unroll
        for (int nt = 0; nt < 4; ++nt)
#pragma unroll
          for (int g = 0; g < 4; ++g) o[s][nt][g] *= ag[g];
      }
    }

    // ---- O += P @ V : swizzled conflict-free Vt b64 reads feed both q-sets
#pragma unroll
    for (int nt = 0; nt < 4; ++nt) {
      int dbase = (kh * 64 + nt * 16 + l16) * 16;
#pragma unroll
      for (int kt = 0; kt < 4; ++kt) {
        f16x4 bv = *(const f16x4*)&Vt[(dbase + ((kt * 4 + quad) ^ l16)) * 4];
#pragma unroll
        for (int s = 0; s < 2; ++s)
          o[s][nt] = __builtin_amdgcn_mfma_f32_16x16x16f16(pa[s][kt], bv, o[s][nt], 0, 0, 0);
      }
    }
  }

  // ---- 4-way merge of key-quarter states per q-pair, then store
  __syncthreads();
  // Osc aliased onto Ks (done with it): [3][2][64] rows of 36 shorts (padded)
  _Float16* Osc = (_Float16*)&Ks[0][0];
  if (kh > 0) {
    const int ki = kh - 1;
#pragma unroll
    for (int s = 0; s < 2; ++s) {
      if (quad == 0) { Msc[ki][qp][s][l16] = m_run[s]; Lsc[ki][qp][s][l16] = l_run[s]; }
#pragma unroll
      for (int nt = 0; nt < 4; ++nt)
#pragma unroll
        for (int g = 0; g < 4; ++g)
          Osc[((ki * 2 + qp) * 64 + lane) * 36 + s * 16 + nt * 4 + g] = (_Float16)o[s][nt][g];
    }
  }
  __syncthreads();
  if (kh == 0) {
#pragma unroll
    for (int s = 0; s < 2; ++s) {
      const float m1 = Msc[0][qp][s][l16], m2 = Msc[1][qp][s][l16], m3 = Msc[2][qp][s][l16];
      const float l1 = Lsc[0][qp][s][l16], l2 = Lsc[1][qp][s][l16], l3 = Lsc[2][qp][s][l16];
      const float m  = fmaxf(fmaxf(m_run[s], m1), fmaxf(m2, m3));
      const float a0 = __expf((m_run[s] - m) * 0.125f);
      const float a1 = __expf((m1 - m) * 0.125f);
      const float a2 = __expf((m2 - m) * 0.125f);
      const float a3 = __expf((m3 - m) * 0.125f);
      const float rl = 1.f / (l_run[s] * a0 + l1 * a1 + l2 * a2 + l3 * a3);
      float a0g[4], a1g[4], a2g[4], a3g[4], rlg[4];
#pragma unroll
      for (int g = 0; g < 4; ++g) {
        int src = quad * 4 + g;
        a0g[g] = __shfl(a0, src);
        a1g[g] = __shfl(a1, src);
        a2g[g] = __shfl(a2, src);
        a3g[g] = __shfl(a3, src);
        rlg[g] = __shfl(rl, src);
      }
#pragma unroll
      for (int g = 0; g < 4; ++g) {
        int row = qbase + s * 16 + quad * 4 + g;
#pragma unroll
        for (int nt = 0; nt < 4; ++nt) {
          int idx = s * 16 + nt * 4 + g;
          float om = o[s][nt][g] * a0g[g]
                   + (float)Osc[((0 + qp) * 64 + lane) * 36 + idx] * a1g[g]
                   + (float)Osc[((2 + qp) * 64 + lane) * 36 + idx] * a2g[g]
                   + (float)Osc[((4 + qp) * 64 + lane) * 36 + idx] * a3g[g];
          Ob[row * DMODEL + hc + nt * 16 + l16] = f2h(om * rlg[g]);
        }
      }
    }
  }
}

// ---------------------------------------------------------------------------
extern "C" void kernel_launch(void* const* d_in, const int* in_sizes, int n_in,
                              void* d_out, int out_size, void* d_ws, size_t ws_size,
                              hipStream_t stream) {
  const float* q  = (const float*)d_in[0];
  const float* k  = (const float*)d_in[1];
  const float* v  = (const float*)d_in[2];
  const float* Wq = (const float*)d_in[3];
  const float* Wk = (const float*)d_in[4];
  const float* Wv = (const float*)d_in[5];
  const float* Wo = (const float*)d_in[6];
  const float* bo = (const float*)d_in[7];

  unsigned short* ws   = (unsigned short*)d_ws;
  unsigned short* Wqt  = ws;                  // 512*512 fp16 each
  unsigned short* Wkt  = Wqt  + 262144;
  unsigned short* Wvt  = Wkt  + 262144;
  unsigned short* Wot  = Wvt  + 262144;
  unsigned short* Wof  = Wot  + 262144;       // straight fp16 Wo
  unsigned short* Wo2t = Wof  + 262144;       // (Wo^2)^T fp16
  unsigned short* Qb   = Wo2t + 262144;       // 4096*512 fp16 each
  unsigned short* Kb   = Qb   + 2097152;
  unsigned short* VtG  = Kb   + 2097152;      // V^T [512][4096] fp16
  unsigned short* Ab   = VtG  + 2097152;      // attention output
  float*          bo2  = (float*)(Ab + 2097152);  // 512 f32
  // high-water ~19.0 MB (ws proven >= 23 MB by rounds 1/3 equivalence)

  wtrans_kernel<<<dim3(8, 8, 4), 256, 0, stream>>>(
      Wq, Wk, Wv, Wo, Wqt, Wkt, Wvt, Wot, Wof);

  // z=0..2: Q/K/V projections (A fp32; V stored transposed);
  // z=3: Wo2t = Wot @ Wof^T (M=512) + bo2 in idle tiles
  gemm_kernel<<<dim3(64, 8, 4), 256, 0, stream>>>(
      q, k, v, Wot, Wqt, Wkt, Wvt, Wof, Qb, Kb, nullptr, Wo2t,
      nullptr, VtG, Wo, bo, bo2, 0x7, 0x0);

  attn_kernel<<<dim3(64, 8), 512, 0, stream>>>(Qb, Kb, VtG, Ab);

  // single fused fc_out: d_out = Ab @ Wo2 + bo2   (fp32 out)
  gemm_kernel<<<dim3(64, 8, 1), 256, 0, stream>>>(
      Ab, nullptr, nullptr, nullptr, Wo2t, nullptr, nullptr, nullptr,
      d_out, nullptr, nullptr, nullptr, bo2, nullptr,
      nullptr, nullptr, nullptr, 0x0, 0x1);
}

// Round 2
// 386.149 us; speedup vs baseline: 1.0116x; 1.0116x over previous
//
#include <hip/hip_runtime.h>

#define S_LEN  4096
#define DMODEL 512
#define NH     8
#define HD     64

typedef _Float16 f16x8 __attribute__((ext_vector_type(8)));
typedef _Float16 f16x4 __attribute__((ext_vector_type(4)));
typedef float    f32x4 __attribute__((ext_vector_type(4)));

static __device__ __forceinline__ unsigned short f2h(float x) {
  return __builtin_bit_cast(unsigned short, (_Float16)x);
}

// ---------------------------------------------------------------------------
// Weight transpose + fp32->fp16: Wt[n][k] = (fp16) W[k][n].  For z==3 (Wo)
// also emits the straight fp16 copy Wof[k][n].  grid (8,8,4) block 256
// ---------------------------------------------------------------------------
__global__ __launch_bounds__(256) void wtrans_kernel(
    const float* __restrict__ w0, const float* __restrict__ w1,
    const float* __restrict__ w2, const float* __restrict__ w3,
    unsigned short* __restrict__ o0, unsigned short* __restrict__ o1,
    unsigned short* __restrict__ o2, unsigned short* __restrict__ o3,
    unsigned short* __restrict__ o3s)
{
  __shared__ unsigned short T[64 * 72];   // T[n_local][k_local], pad 72
  const float* W; unsigned short* O;
  switch (blockIdx.z) {
    case 0:  W = w0; O = o0; break;
    case 1:  W = w1; O = o1; break;
    case 2:  W = w2; O = o2; break;
    default: W = w3; O = o3; break;
  }
  const int tid = threadIdx.x;
  const int k0 = blockIdx.x * 64, n0 = blockIdx.y * 64;
  const int c4 = (tid & 15) * 4;
#pragma unroll
  for (int rp = 0; rp < 4; ++rp) {
    int r = rp * 16 + (tid >> 4);
    float4 x = *(const float4*)(W + (k0 + r) * DMODEL + n0 + c4);
    T[(c4 + 0) * 72 + r] = f2h(x.x);
    T[(c4 + 1) * 72 + r] = f2h(x.y);
    T[(c4 + 2) * 72 + r] = f2h(x.z);
    T[(c4 + 3) * 72 + r] = f2h(x.w);
    if (blockIdx.z == 3) {
      f16x4 st;
      st[0] = (_Float16)x.x; st[1] = (_Float16)x.y;
      st[2] = (_Float16)x.z; st[3] = (_Float16)x.w;
      *(f16x4*)&o3s[(k0 + r) * DMODEL + n0 + c4] = st;
    }
  }
  __syncthreads();
#pragma unroll
  for (int it = 0; it < 2; ++it) {
    int i = tid + it * 256;
    int nl = i >> 3, c = i & 7;
    *(f16x8*)&O[(n0 + nl) * DMODEL + k0 + c * 8] = *(const f16x8*)&T[nl * 72 + c * 8];
  }
}

// ---------------------------------------------------------------------------
// GEMM (multi-op): blockIdx.z selects (A,Bt,C). Body = round-2-proven kernel.
// z==3 limited to 8 M-tiles (M=512); idle z==3 blocks compute bo2.
// vtg!=null && z==2: C stored transposed (V^T). grid (64,8,nz) block 256.
// ---------------------------------------------------------------------------
__global__ __launch_bounds__(256) void gemm_kernel(
    const void* __restrict__ A0, const void* __restrict__ A1,
    const void* __restrict__ A2, const void* __restrict__ A3,
    const unsigned short* __restrict__ B0, const unsigned short* __restrict__ B1,
    const unsigned short* __restrict__ B2, const unsigned short* __restrict__ B3,
    void* __restrict__ C0, void* __restrict__ C1,
    void* __restrict__ C2, void* __restrict__ C3,
    const float* __restrict__ bias, unsigned short* __restrict__ vtg,
    const float* __restrict__ wo_f32, const float* __restrict__ bo_in,
    float* __restrict__ bo2_out,
    int a_fp32_mask, int c_fp32_mask)
{
  constexpr int K = DMODEL, N = DMODEL;
  __shared__ unsigned short As[64 * 32];
  __shared__ unsigned short Bs[64 * 32];
  const int z = blockIdx.z;
  if (z == 3 && blockIdx.x >= 8) {          // idle tiles: bo2 side-job
    if (blockIdx.x < 16 && blockIdx.y == 0 && wo_f32) {
      int col = (blockIdx.x - 8) * 64 + (threadIdx.x & 63);
      float s = bo_in[col];
#pragma unroll 8
      for (int j = 0; j < DMODEL; ++j) s = fmaf(bo_in[j], wo_f32[j * DMODEL + col], s);
      bo2_out[col] = s;
    }
    return;
  }
  const void* Av; const unsigned short* Bt; void* Cv;
  switch (z) {
    case 0:  Av = A0; Bt = B0; Cv = C0; break;
    case 1:  Av = A1; Bt = B1; Cv = C1; break;
    case 2:  Av = A2; Bt = B2; Cv = C2; break;
    default: Av = A3; Bt = B3; Cv = C3; break;
  }
  const int a_fp32 = (a_fp32_mask >> z) & 1;
  const int c_fp32 = (c_fp32_mask >> z) & 1;
  const int tid  = threadIdx.x;
  const int lane = tid & 63;
  const int wid  = tid >> 6;
  const int quad = lane >> 4, l16 = lane & 15;
  const int m0 = blockIdx.x * 64, n0 = blockIdx.y * 64;
  const int wm = (wid >> 1) * 32, wn = (wid & 1) * 32;
  const int r  = tid >> 2, ck = (tid & 3) * 8;   // staging: row, k-offset
  f32x4 acc[2][2] = {};

  for (int k0 = 0; k0 < K; k0 += 32) {
    __syncthreads();
    if (a_fp32) {
      const float* p = (const float*)Av + (m0 + r) * K + k0 + ck;
      float4 x = *(const float4*)p;
      float4 y = *(const float4*)(p + 4);
      f16x8 av;
      av[0] = (_Float16)x.x; av[1] = (_Float16)x.y;
      av[2] = (_Float16)x.z; av[3] = (_Float16)x.w;
      av[4] = (_Float16)y.x; av[5] = (_Float16)y.y;
      av[6] = (_Float16)y.z; av[7] = (_Float16)y.w;
      *(f16x8*)&As[r * 32 + ck] = av;
    } else {
      *(f16x8*)&As[r * 32 + ck] =
          *(const f16x8*)((const unsigned short*)Av + (m0 + r) * K + k0 + ck);
    }
    *(f16x8*)&Bs[r * 32 + ck] = *(const f16x8*)(Bt + (n0 + r) * K + k0 + ck);
    __syncthreads();

    f16x8 a0 = *(const f16x8*)&As[(wm + l16) * 32 + quad * 8];
    f16x8 a1 = *(const f16x8*)&As[(wm + 16 + l16) * 32 + quad * 8];
    f16x8 b0 = *(const f16x8*)&Bs[(wn + l16) * 32 + quad * 8];
    f16x8 b1 = *(const f16x8*)&Bs[(wn + 16 + l16) * 32 + quad * 8];
    acc[0][0] = __builtin_amdgcn_mfma_f32_16x16x32_f16(a0, b0, acc[0][0], 0, 0, 0);
    acc[0][1] = __builtin_amdgcn_mfma_f32_16x16x32_f16(a0, b1, acc[0][1], 0, 0, 0);
    acc[1][0] = __builtin_amdgcn_mfma_f32_16x16x32_f16(a1, b0, acc[1][0], 0, 0, 0);
    acc[1][1] = __builtin_amdgcn_mfma_f32_16x16x32_f16(a1, b1, acc[1][1], 0, 0, 0);
  }

  const int do_vt = (vtg != nullptr) && (z == 2);
#pragma unroll
  for (int mt = 0; mt < 2; ++mt)
#pragma unroll
    for (int nt = 0; nt < 2; ++nt) {
      int col = n0 + wn + nt * 16 + l16;
      float bv = bias ? bias[col] : 0.f;
#pragma unroll
      for (int g = 0; g < 4; ++g) {
        int row = m0 + wm + mt * 16 + quad * 4 + g;   // C/D: row = quad*4+reg
        float val = acc[mt][nt][g] + bv;
        if (do_vt)        vtg[col * S_LEN + row] = f2h(val);      // V^T[d][key]
        else if (c_fp32)  ((float*)Cv)[row * N + col] = val;
        else              ((unsigned short*)Cv)[row * N + col] = f2h(val);
      }
    }
}

// ---------------------------------------------------------------------------
// Split-K MFMA flash attention, S^T formulation, 2 q-sets per wave.
// 8-wave blocks (512 thr) = 2 q-pairs x 4 key-quarters; 2 blocks/CU =
// 16 waves/CU. ROUND FIX: __launch_bounds__(512,4) was interpreted as
// 4 blocks/CU -> 64-VGPR cap -> 722 MB scratch spill (WRITE_SIZE counter).
// Now __launch_bounds__(512) + amdgpu_waves_per_eu(4): hard 128-VGPR cap,
// natural ~112 allocation, no spill, still 2 blocks/CU at LDS 69.5 KB.
// Vt stored XOR-swizzled (u = d*16 + ((2c+j)^(d&15))): conflict-free
// ds_read_b64 in PV (verified: conflicts 6.4M -> 2.1M).
// Defer-max (THR=8 raw): skip alpha/rescale when tile max doesn't grow.
// 4-way kh merge via LDS scratch aliased onto Ks. grid (64, 8).
// ---------------------------------------------------------------------------
__global__ __launch_bounds__(512) __attribute__((amdgpu_waves_per_eu(4)))
void attn_kernel(
    const unsigned short* __restrict__ Qb, const unsigned short* __restrict__ Kb,
    const unsigned short* __restrict__ VtG, unsigned short* __restrict__ Ob)
{
  __shared__ unsigned short Ks[4][64 * 72];   // K[n][k] per quarter, pad 72
  __shared__ unsigned short Vt[4 * 64 * 64];  // V^T swizzled, stride 64, no pad
  __shared__ float Msc[3][2][2][16];          // merge scratch m [ki][qp][s][l16]
  __shared__ float Lsc[3][2][2][16];          // merge scratch l

  const int tid  = threadIdx.x;
  const int lane = tid & 63;
  const int wid  = tid >> 6;        // 0..7
  const int qp   = wid & 1;         // q-pair (32 q-rows)
  const int kh   = wid >> 1;        // key quarter 0..3
  const int quad = lane >> 4, l16 = lane & 15;
  const int qb = blockIdx.x, h = blockIdx.y;
  const int hc = h * HD;
  const int qbase = qb * 64 + qp * 32;

  // Persistent Q fragments (B operand), 2 sets: Q[q=l16][d=quad*8+j (+32)]
  f16x8 bq[2][2];
#pragma unroll
  for (int s = 0; s < 2; ++s) {
    int qrow = qbase + s * 16 + l16;
    bq[s][0] = *(const f16x8*)(Qb + qrow * DMODEL + hc + quad * 8);
    bq[s][1] = *(const f16x8*)(Qb + qrow * DMODEL + hc + 32 + quad * 8);
  }

  // o[s][nt] holds O[q = quad*4+g][d = nt*16 + l16] for set s
  f32x4 o[2][4] = {};
  float m_run[2] = {-1e30f, -1e30f}, l_run[2] = {0.f, 0.f};

  // staging decomposition (512 threads, 2048 chunks per array):
  // it in 0..3: s = it*512+tid; sub = s>>9; n = (s>>3)&63; c = s&7
  // key quarter `sub` covers global keys sub*1024 + kb .. +63
  f16x8 kreg[4], vreg[4];
#pragma unroll
  for (int it = 0; it < 4; ++it) {     // prefetch kb = 0
    int s = it * 512 + tid;
    int sub = s >> 9, n = (s >> 3) & 63, c = s & 7;
    kreg[it] = *(const f16x8*)(Kb + (sub * 1024 + n) * DMODEL + hc + c * 8);
    vreg[it] = *(const f16x8*)(VtG + (hc + n) * S_LEN + sub * 1024 + c * 8);
  }

  for (int kbi = 0; kbi < 16; ++kbi) {
    __syncthreads();                   // all waves done reading previous tiles
#pragma unroll
    for (int it = 0; it < 4; ++it) {
      int s = it * 512 + tid;
      int sub = s >> 9, n = (s >> 3) & 63, c = s & 7;
      *(f16x8*)&Ks[sub][n * 72 + c * 8] = kreg[it];
      // swizzled Vt: element [d=n][k=8c+4*j2+jj] at u=(sub*64+n)*16+((2c+j2)^(n&15))
      int vbase = (sub * 64 + n) * 16;
      int n15 = n & 15;
      f16x4 lo = __builtin_shufflevector(vreg[it], vreg[it], 0, 1, 2, 3);
      f16x4 hi = __builtin_shufflevector(vreg[it], vreg[it], 4, 5, 6, 7);
      *(f16x4*)&Vt[(vbase + ((2 * c) ^ n15)) * 4]     = lo;
      *(f16x4*)&Vt[(vbase + ((2 * c + 1) ^ n15)) * 4] = hi;
    }
    __syncthreads();                   // staging visible

    if (kbi + 1 < 16) {                // prefetch next chunk into registers
      int kb1 = (kbi + 1) * 64;
#pragma unroll
      for (int it = 0; it < 4; ++it) {
        int s = it * 512 + tid;
        int sub = s >> 9, n = (s >> 3) & 63, c = s & 7;
        kreg[it] = *(const f16x8*)(Kb + (sub * 1024 + kb1 + n) * DMODEL + hc + c * 8);
        vreg[it] = *(const f16x8*)(VtG + (hc + n) * S_LEN + sub * 1024 + kb1 + c * 8);
      }
    }

    // ---- S^T = K Q^T : one Ks read feeds both q-sets
    f32x4 sT[2][4];
#pragma unroll
    for (int kt = 0; kt < 4; ++kt) {
      f16x8 ak0 = *(const f16x8*)&Ks[kh][(kt * 16 + l16) * 72 + quad * 8];
      f16x8 ak1 = *(const f16x8*)&Ks[kh][(kt * 16 + l16) * 72 + 32 + quad * 8];
#pragma unroll
      for (int s = 0; s < 2; ++s) {
        f32x4 a = {};
        a = __builtin_amdgcn_mfma_f32_16x16x32_f16(ak0, bq[s][0], a, 0, 0, 0);
        a = __builtin_amdgcn_mfma_f32_16x16x32_f16(ak1, bq[s][1], a, 0, 0, 0);
        sT[s][kt] = a;
      }
    }

    // ---- online softmax per set (scale 1/8 folded into exp), defer-max
    f16x4 pa[2][4];
#pragma unroll
    for (int s = 0; s < 2; ++s) {
      float vmax = -1e30f;
#pragma unroll
      for (int kt = 0; kt < 4; ++kt)
#pragma unroll
        for (int g = 0; g < 4; ++g) vmax = fmaxf(vmax, sT[s][kt][g]);
      vmax = fmaxf(vmax, __shfl_xor(vmax, 16));
      vmax = fmaxf(vmax, __shfl_xor(vmax, 32));

      if (__all(vmax <= m_run[s] + 8.0f)) {
        // deferred: keep old max, no rescale; p bounded by e^1
        const float mn = m_run[s];
        float rs = 0.f;
#pragma unroll
        for (int kt = 0; kt < 4; ++kt)
#pragma unroll
          for (int g = 0; g < 4; ++g) {
            float p = __expf((sT[s][kt][g] - mn) * 0.125f);
            rs += p;
            pa[s][kt][g] = (_Float16)p;
          }
        rs += __shfl_xor(rs, 16);
        rs += __shfl_xor(rs, 32);
        l_run[s] += rs;
      } else {
        const float mn = fmaxf(m_run[s], vmax);
        const float alpha = __expf((m_run[s] - mn) * 0.125f);
        m_run[s] = mn;

        float rs = 0.f;
#pragma unroll
        for (int kt = 0; kt < 4; ++kt)
#pragma unroll
          for (int g = 0; g < 4; ++g) {
            float p = __expf((sT[s][kt][g] - mn) * 0.125f);
            rs += p;
            pa[s][kt][g] = (_Float16)p;
          }
        rs += __shfl_xor(rs, 16);
        rs += __shfl_xor(rs, 32);
        l_run[s] = l_run[s] * alpha + rs;

        float ag[4];
#pragma unroll
        for (int g = 0; g < 4; ++g) ag[g] = __shfl(alpha, quad * 4 + g);
#pragma unroll
        for (int nt = 0; nt < 4; ++nt)
#pragma unroll
          for (int g = 0; g < 4; ++g) o[s][nt][g] *= ag[g];
      }
    }

    // ---- O += P @ V : swizzled conflict-free Vt b64 reads feed both q-sets
#pragma unroll
    for (int nt = 0; nt < 4; ++nt) {
      int dbase = (kh * 64 + nt * 16 + l16) * 16;
#pragma unroll
      for (int kt = 0; kt < 4; ++kt) {
        f16x4 bv = *(const f16x4*)&Vt[(dbase + ((kt * 4 + quad) ^ l16)) * 4];
#pragma unroll
        for (int s = 0; s < 2; ++s)
          o[s][nt] = __builtin_amdgcn_mfma_f32_16x16x16f16(pa[s][kt], bv, o[s][nt], 0, 0, 0);
      }
    }
  }

  // ---- 4-way merge of key-quarter states per q-pair, then store
  __syncthreads();
  // Osc aliased onto Ks (done with it): [3][2][64] rows of 36 shorts (padded)
  _Float16* Osc = (_Float16*)&Ks[0][0];
  if (kh > 0) {
    const int ki = kh - 1;
#pragma unroll
    for (int s = 0; s < 2; ++s) {
      if (quad == 0) { Msc[ki][qp][s][l16] = m_run[s]; Lsc[ki][qp][s][l16] = l_run[s]; }
#pragma unroll
      for (int nt = 0; nt < 4; ++nt)
#pragma unroll
        for (int g = 0; g < 4; ++g)
          Osc[((ki * 2 + qp) * 64 + lane) * 36 + s * 16 + nt * 4 + g] = (_Float16)o[s][nt][g];
    }
  }
  __syncthreads();
  if (kh == 0) {
#pragma unroll
    for (int s = 0; s < 2; ++s) {
      const float m1 = Msc[0][qp][s][l16], m2 = Msc[1][qp][s][l16], m3 = Msc[2][qp][s][l16];
      const float l1 = Lsc[0][qp][s][l16], l2 = Lsc[1][qp][s][l16], l3 = Lsc[2][qp][s][l16];
      const float m  = fmaxf(fmaxf(m_run[s], m1), fmaxf(m2, m3));
      const float a0 = __expf((m_run[s] - m) * 0.125f);
      const float a1 = __expf((m1 - m) * 0.125f);
      const float a2 = __expf((m2 - m) * 0.125f);
      const float a3 = __expf((m3 - m) * 0.125f);
      const float rl = 1.f / (l_run[s] * a0 + l1 * a1 + l2 * a2 + l3 * a3);
      float a0g[4], a1g[4], a2g[4], a3g[4], rlg[4];
#pragma unroll
      for (int g = 0; g < 4; ++g) {
        int src = quad * 4 + g;
        a0g[g] = __shfl(a0, src);
        a1g[g] = __shfl(a1, src);
        a2g[g] = __shfl(a2, src);
        a3g[g] = __shfl(a3, src);
        rlg[g] = __shfl(rl, src);
      }
#pragma unroll
      for (int g = 0; g < 4; ++g) {
        int row = qbase + s * 16 + quad * 4 + g;
#pragma unroll
        for (int nt = 0; nt < 4; ++nt) {
          int idx = s * 16 + nt * 4 + g;
          float om = o[s][nt][g] * a0g[g]
                   + (float)Osc[((0 + qp) * 64 + lane) * 36 + idx] * a1g[g]
                   + (float)Osc[((2 + qp) * 64 + lane) * 36 + idx] * a2g[g]
                   + (float)Osc[((4 + qp) * 64 + lane) * 36 + idx] * a3g[g];
          Ob[row * DMODEL + hc + nt * 16 + l16] = f2h(om * rlg[g]);
        }
      }
    }
  }
}

// ---------------------------------------------------------------------------
extern "C" void kernel_launch(void* const* d_in, const int* in_sizes, int n_in,
                              void* d_out, int out_size, void* d_ws, size_t ws_size,
                              hipStream_t stream) {
  const float* q  = (const float*)d_in[0];
  const float* k  = (const float*)d_in[1];
  const float* v  = (const float*)d_in[2];
  const float* Wq = (const float*)d_in[3];
  const float* Wk = (const float*)d_in[4];
  const float* Wv = (const float*)d_in[5];
  const float* Wo = (const float*)d_in[6];
  const float* bo = (const float*)d_in[7];

  unsigned short* ws   = (unsigned short*)d_ws;
  unsigned short* Wqt  = ws;                  // 512*512 fp16 each
  unsigned short* Wkt  = Wqt  + 262144;
  unsigned short* Wvt  = Wkt  + 262144;
  unsigned short* Wot  = Wvt  + 262144;
  unsigned short* Wof  = Wot  + 262144;       // straight fp16 Wo
  unsigned short* Wo2t = Wof  + 262144;       // (Wo^2)^T fp16
  unsigned short* Qb   = Wo2t + 262144;       // 4096*512 fp16 each
  unsigned short* Kb   = Qb   + 2097152;
  unsigned short* VtG  = Kb   + 2097152;      // V^T [512][4096] fp16
  unsigned short* Ab   = VtG  + 2097152;      // attention output
  float*          bo2  = (float*)(Ab + 2097152);  // 512 f32
  // high-water ~19.0 MB (ws proven >= 23 MB by rounds 1/3 equivalence)

  wtrans_kernel<<<dim3(8, 8, 4), 256, 0, stream>>>(
      Wq, Wk, Wv, Wo, Wqt, Wkt, Wvt, Wot, Wof);

  // z=0..2: Q/K/V projections (A fp32; V stored transposed);
  // z=3: Wo2t = Wot @ Wof^T (M=512) + bo2 in idle tiles
  gemm_kernel<<<dim3(64, 8, 4), 256, 0, stream>>>(
      q, k, v, Wot, Wqt, Wkt, Wvt, Wof, Qb, Kb, nullptr, Wo2t,
      nullptr, VtG, Wo, bo, bo2, 0x7, 0x0);

  attn_kernel<<<dim3(64, 8), 512, 0, stream>>>(Qb, Kb, VtG, Ab);

  // single fused fc_out: d_out = Ab @ Wo2 + bo2   (fp32 out)
  gemm_kernel<<<dim3(64, 8, 1), 256, 0, stream>>>(
      Ab, nullptr, nullptr, nullptr, Wo2t, nullptr, nullptr, nullptr,
      d_out, nullptr, nullptr, nullptr, bo2, nullptr,
      nullptr, nullptr, nullptr, 0x0, 0x1);
}

// Round 3
// 213.581 us; speedup vs baseline: 1.8290x; 1.8080x over previous
//
#include <hip/hip_runtime.h>

#define S_LEN  4096
#define DMODEL 512
#define NH     8
#define HD     64

typedef _Float16 f16x8 __attribute__((ext_vector_type(8)));
typedef _Float16 f16x4 __attribute__((ext_vector_type(4)));
typedef float    f32x4 __attribute__((ext_vector_type(4)));

static __device__ __forceinline__ unsigned short f2h(float x) {
  return __builtin_bit_cast(unsigned short, (_Float16)x);
}

// ---------------------------------------------------------------------------
// Weight transpose + fp32->fp16: Wt[n][k] = (fp16) W[k][n].  For z==3 (Wo)
// also emits the straight fp16 copy Wof[k][n].  grid (8,8,4) block 256
// ---------------------------------------------------------------------------
__global__ __launch_bounds__(256) void wtrans_kernel(
    const float* __restrict__ w0, const float* __restrict__ w1,
    const float* __restrict__ w2, const float* __restrict__ w3,
    unsigned short* __restrict__ o0, unsigned short* __restrict__ o1,
    unsigned short* __restrict__ o2, unsigned short* __restrict__ o3,
    unsigned short* __restrict__ o3s)
{
  __shared__ unsigned short T[64 * 72];   // T[n_local][k_local], pad 72
  const float* W; unsigned short* O;
  switch (blockIdx.z) {
    case 0:  W = w0; O = o0; break;
    case 1:  W = w1; O = o1; break;
    case 2:  W = w2; O = o2; break;
    default: W = w3; O = o3; break;
  }
  const int tid = threadIdx.x;
  const int k0 = blockIdx.x * 64, n0 = blockIdx.y * 64;
  const int c4 = (tid & 15) * 4;
#pragma unroll
  for (int rp = 0; rp < 4; ++rp) {
    int r = rp * 16 + (tid >> 4);
    float4 x = *(const float4*)(W + (k0 + r) * DMODEL + n0 + c4);
    T[(c4 + 0) * 72 + r] = f2h(x.x);
    T[(c4 + 1) * 72 + r] = f2h(x.y);
    T[(c4 + 2) * 72 + r] = f2h(x.z);
    T[(c4 + 3) * 72 + r] = f2h(x.w);
    if (blockIdx.z == 3) {
      f16x4 st;
      st[0] = (_Float16)x.x; st[1] = (_Float16)x.y;
      st[2] = (_Float16)x.z; st[3] = (_Float16)x.w;
      *(f16x4*)&o3s[(k0 + r) * DMODEL + n0 + c4] = st;
    }
  }
  __syncthreads();
#pragma unroll
  for (int it = 0; it < 2; ++it) {
    int i = tid + it * 256;
    int nl = i >> 3, c = i & 7;
    *(f16x8*)&O[(n0 + nl) * DMODEL + k0 + c * 8] = *(const f16x8*)&T[nl * 72 + c * 8];
  }
}

// ---------------------------------------------------------------------------
// GEMM (multi-op): blockIdx.z selects (A,Bt,C). Body = round-2-proven kernel.
// z==3 limited to 8 M-tiles (M=512); idle z==3 blocks compute bo2.
// vtg!=null && z==2: C stored transposed (V^T). grid (64,8,nz) block 256.
// ---------------------------------------------------------------------------
__global__ __launch_bounds__(256) void gemm_kernel(
    const void* __restrict__ A0, const void* __restrict__ A1,
    const void* __restrict__ A2, const void* __restrict__ A3,
    const unsigned short* __restrict__ B0, const unsigned short* __restrict__ B1,
    const unsigned short* __restrict__ B2, const unsigned short* __restrict__ B3,
    void* __restrict__ C0, void* __restrict__ C1,
    void* __restrict__ C2, void* __restrict__ C3,
    const float* __restrict__ bias, unsigned short* __restrict__ vtg,
    const float* __restrict__ wo_f32, const float* __restrict__ bo_in,
    float* __restrict__ bo2_out,
    int a_fp32_mask, int c_fp32_mask)
{
  constexpr int K = DMODEL, N = DMODEL;
  __shared__ unsigned short As[64 * 32];
  __shared__ unsigned short Bs[64 * 32];
  const int z = blockIdx.z;
  if (z == 3 && blockIdx.x >= 8) {          // idle tiles: bo2 side-job
    if (blockIdx.x < 16 && blockIdx.y == 0 && wo_f32) {
      int col = (blockIdx.x - 8) * 64 + (threadIdx.x & 63);
      float s = bo_in[col];
#pragma unroll 8
      for (int j = 0; j < DMODEL; ++j) s = fmaf(bo_in[j], wo_f32[j * DMODEL + col], s);
      bo2_out[col] = s;
    }
    return;
  }
  const void* Av; const unsigned short* Bt; void* Cv;
  switch (z) {
    case 0:  Av = A0; Bt = B0; Cv = C0; break;
    case 1:  Av = A1; Bt = B1; Cv = C1; break;
    case 2:  Av = A2; Bt = B2; Cv = C2; break;
    default: Av = A3; Bt = B3; Cv = C3; break;
  }
  const int a_fp32 = (a_fp32_mask >> z) & 1;
  const int c_fp32 = (c_fp32_mask >> z) & 1;
  const int tid  = threadIdx.x;
  const int lane = tid & 63;
  const int wid  = tid >> 6;
  const int quad = lane >> 4, l16 = lane & 15;
  const int m0 = blockIdx.x * 64, n0 = blockIdx.y * 64;
  const int wm = (wid >> 1) * 32, wn = (wid & 1) * 32;
  const int r  = tid >> 2, ck = (tid & 3) * 8;   // staging: row, k-offset
  f32x4 acc[2][2] = {};

  for (int k0 = 0; k0 < K; k0 += 32) {
    __syncthreads();
    if (a_fp32) {
      const float* p = (const float*)Av + (m0 + r) * K + k0 + ck;
      float4 x = *(const float4*)p;
      float4 y = *(const float4*)(p + 4);
      f16x8 av;
      av[0] = (_Float16)x.x; av[1] = (_Float16)x.y;
      av[2] = (_Float16)x.z; av[3] = (_Float16)x.w;
      av[4] = (_Float16)y.x; av[5] = (_Float16)y.y;
      av[6] = (_Float16)y.z; av[7] = (_Float16)y.w;
      *(f16x8*)&As[r * 32 + ck] = av;
    } else {
      *(f16x8*)&As[r * 32 + ck] =
          *(const f16x8*)((const unsigned short*)Av + (m0 + r) * K + k0 + ck);
    }
    *(f16x8*)&Bs[r * 32 + ck] = *(const f16x8*)(Bt + (n0 + r) * K + k0 + ck);
    __syncthreads();

    f16x8 a0 = *(const f16x8*)&As[(wm + l16) * 32 + quad * 8];
    f16x8 a1 = *(const f16x8*)&As[(wm + 16 + l16) * 32 + quad * 8];
    f16x8 b0 = *(const f16x8*)&Bs[(wn + l16) * 32 + quad * 8];
    f16x8 b1 = *(const f16x8*)&Bs[(wn + 16 + l16) * 32 + quad * 8];
    acc[0][0] = __builtin_amdgcn_mfma_f32_16x16x32_f16(a0, b0, acc[0][0], 0, 0, 0);
    acc[0][1] = __builtin_amdgcn_mfma_f32_16x16x32_f16(a0, b1, acc[0][1], 0, 0, 0);
    acc[1][0] = __builtin_amdgcn_mfma_f32_16x16x32_f16(a1, b0, acc[1][0], 0, 0, 0);
    acc[1][1] = __builtin_amdgcn_mfma_f32_16x16x32_f16(a1, b1, acc[1][1], 0, 0, 0);
  }

  const int do_vt = (vtg != nullptr) && (z == 2);
#pragma unroll
  for (int mt = 0; mt < 2; ++mt)
#pragma unroll
    for (int nt = 0; nt < 2; ++nt) {
      int col = n0 + wn + nt * 16 + l16;
      float bv = bias ? bias[col] : 0.f;
#pragma unroll
      for (int g = 0; g < 4; ++g) {
        int row = m0 + wm + mt * 16 + quad * 4 + g;   // C/D: row = quad*4+reg
        float val = acc[mt][nt][g] + bv;
        if (do_vt)        vtg[col * S_LEN + row] = f2h(val);      // V^T[d][key]
        else if (c_fp32)  ((float*)Cv)[row * N + col] = val;
        else              ((unsigned short*)Cv)[row * N + col] = f2h(val);
      }
    }
}

// ---------------------------------------------------------------------------
// Split-K MFMA flash attention, S^T formulation, 2 q-sets per wave,
// register-prefetched staging. Round-0 proven 256-thread body (VGPR 112,
// no spill), now key-split ACROSS blocks: grid (64, 8, 2) = 1024 blocks,
// z handles keys [z*2048, z*2048+2048) as 2 kh-halves of 1024 (16 iters).
// 1024 blocks = 4 blocks/CU = 4 waves/SIMD (was 2) -- occupancy from the
// grid, no waves_per_eu attributes (both interpretations produced a
// 64-VGPR cap + 722 MB spill in rounds 1-2).
// LDS 35.3 KB (4x fits 160 KB): Vt XOR-swizzled stride-64 (conflict-free
// ds_read_b64 in PV, validated rounds 1-2), merge scratch aliased on Ks.
// Partials: z=0 -> f32 in d_out (scratch until final gemm), z=1 -> fp16
// in Ab; per-row (m,l) to ws. merge_kernel combines into Ab.
// ---------------------------------------------------------------------------
__global__ __launch_bounds__(256) void attn_kernel(
    const unsigned short* __restrict__ Qb, const unsigned short* __restrict__ Kb,
    const unsigned short* __restrict__ VtG,
    float* __restrict__ P0, unsigned short* __restrict__ P1,
    float* __restrict__ mp, float* __restrict__ lp)
{
  __shared__ unsigned short Ks[2][64 * 72];   // K[n][k] per half, pad 72
  __shared__ unsigned short Vt[2 * 64 * 64];  // V^T swizzled, stride 64, no pad
  __shared__ float Msc[2][2][16];             // merge scratch m [qp][s][l16]
  __shared__ float Lsc[2][2][16];             // merge scratch l

  const int tid  = threadIdx.x;
  const int lane = tid & 63;
  const int wid  = tid >> 6;        // 0..3
  const int qp   = wid & 1;         // q-pair (32 q-rows)
  const int kh   = wid >> 1;        // 1024-key half within this z-chunk
  const int quad = lane >> 4, l16 = lane & 15;
  const int qb = blockIdx.x, h = blockIdx.y, z = blockIdx.z;
  const int hc = h * HD;
  const int qbase = qb * 64 + qp * 32;
  const int kz = z * 2048;

  // Persistent Q fragments (B operand), 2 sets: Q[q=l16][d=quad*8+j (+32)]
  f16x8 bq[2][2];
#pragma unroll
  for (int s = 0; s < 2; ++s) {
    int qrow = qbase + s * 16 + l16;
    bq[s][0] = *(const f16x8*)(Qb + qrow * DMODEL + hc + quad * 8);
    bq[s][1] = *(const f16x8*)(Qb + qrow * DMODEL + hc + 32 + quad * 8);
  }

  // o[s][nt] holds O[q = quad*4+g][d = nt*16 + l16] for set s
  f32x4 o[2][4] = {};
  float m_run[2] = {-1e30f, -1e30f}, l_run[2] = {0.f, 0.f};

  // staging decomposition (256 threads, 1024 chunks per array):
  // it in 0..3: s = it*256+tid; khs = s>>9; n = (s>>3)&63; c = s&7
  f16x8 kreg[4], vreg[4];
#pragma unroll
  for (int it = 0; it < 4; ++it) {     // prefetch kbi = 0
    int s = it * 256 + tid;
    int khs = s >> 9, n = (s >> 3) & 63, c = s & 7;
    kreg[it] = *(const f16x8*)(Kb + (kz + khs * 1024 + n) * DMODEL + hc + c * 8);
    vreg[it] = *(const f16x8*)(VtG + (hc + n) * S_LEN + kz + khs * 1024 + c * 8);
  }

  for (int kbi = 0; kbi < 16; ++kbi) {
    __syncthreads();                   // all waves done reading previous tiles
#pragma unroll
    for (int it = 0; it < 4; ++it) {
      int s = it * 256 + tid;
      int khs = s >> 9, n = (s >> 3) & 63, c = s & 7;
      *(f16x8*)&Ks[khs][n * 72 + c * 8] = kreg[it];
      // swizzled Vt: granule (2c+j) of row d=n at u=(khs*64+n)*16+((2c+j)^(n&15))
      int vbase = (khs * 64 + n) * 16;
      int n15 = n & 15;
      f16x4 lo = __builtin_shufflevector(vreg[it], vreg[it], 0, 1, 2, 3);
      f16x4 hi = __builtin_shufflevector(vreg[it], vreg[it], 4, 5, 6, 7);
      *(f16x4*)&Vt[(vbase + ((2 * c) ^ n15)) * 4]     = lo;
      *(f16x4*)&Vt[(vbase + ((2 * c + 1) ^ n15)) * 4] = hi;
    }
    __syncthreads();                   // staging visible

    if (kbi + 1 < 16) {                // prefetch next chunk into registers
      int kb1 = (kbi + 1) * 64;
#pragma unroll
      for (int it = 0; it < 4; ++it) {
        int s = it * 256 + tid;
        int khs = s >> 9, n = (s >> 3) & 63, c = s & 7;
        kreg[it] = *(const f16x8*)(Kb + (kz + khs * 1024 + kb1 + n) * DMODEL + hc + c * 8);
        vreg[it] = *(const f16x8*)(VtG + (hc + n) * S_LEN + kz + khs * 1024 + kb1 + c * 8);
      }
    }

    // ---- S^T = K Q^T : one Ks read feeds both q-sets
    f32x4 sT[2][4];
#pragma unroll
    for (int kt = 0; kt < 4; ++kt) {
      f16x8 ak0 = *(const f16x8*)&Ks[kh][(kt * 16 + l16) * 72 + quad * 8];
      f16x8 ak1 = *(const f16x8*)&Ks[kh][(kt * 16 + l16) * 72 + 32 + quad * 8];
#pragma unroll
      for (int s = 0; s < 2; ++s) {
        f32x4 a = {};
        a = __builtin_amdgcn_mfma_f32_16x16x32_f16(ak0, bq[s][0], a, 0, 0, 0);
        a = __builtin_amdgcn_mfma_f32_16x16x32_f16(ak1, bq[s][1], a, 0, 0, 0);
        sT[s][kt] = a;
      }
    }

    // ---- online softmax per set (scale 1/8 folded into exp), defer-max
    f16x4 pa[2][4];
#pragma unroll
    for (int s = 0; s < 2; ++s) {
      float vmax = -1e30f;
#pragma unroll
      for (int kt = 0; kt < 4; ++kt)
#pragma unroll
        for (int g = 0; g < 4; ++g) vmax = fmaxf(vmax, sT[s][kt][g]);
      vmax = fmaxf(vmax, __shfl_xor(vmax, 16));
      vmax = fmaxf(vmax, __shfl_xor(vmax, 32));

      if (__all(vmax <= m_run[s] + 8.0f)) {
        // deferred: keep old max, no rescale; p bounded by e^1
        const float mn = m_run[s];
        float rs = 0.f;
#pragma unroll
        for (int kt = 0; kt < 4; ++kt)
#pragma unroll
          for (int g = 0; g < 4; ++g) {
            float p = __expf((sT[s][kt][g] - mn) * 0.125f);
            rs += p;
            pa[s][kt][g] = (_Float16)p;
          }
        rs += __shfl_xor(rs, 16);
        rs += __shfl_xor(rs, 32);
        l_run[s] += rs;
      } else {
        const float mn = fmaxf(m_run[s], vmax);
        const float alpha = __expf((m_run[s] - mn) * 0.125f);
        m_run[s] = mn;

        float rs = 0.f;
#pragma unroll
        for (int kt = 0; kt < 4; ++kt)
#pragma unroll
          for (int g = 0; g < 4; ++g) {
            float p = __expf((sT[s][kt][g] - mn) * 0.125f);
            rs += p;
            pa[s][kt][g] = (_Float16)p;
          }
        rs += __shfl_xor(rs, 16);
        rs += __shfl_xor(rs, 32);
        l_run[s] = l_run[s] * alpha + rs;

        float ag[4];
#pragma unroll
        for (int g = 0; g < 4; ++g) ag[g] = __shfl(alpha, quad * 4 + g);
#pragma unroll
        for (int nt = 0; nt < 4; ++nt)
#pragma unroll
          for (int g = 0; g < 4; ++g) o[s][nt][g] *= ag[g];
      }
    }

    // ---- O += P @ V : swizzled conflict-free Vt b64 reads feed both q-sets
#pragma unroll
    for (int nt = 0; nt < 4; ++nt) {
      int dbase = (kh * 64 + nt * 16 + l16) * 16;
#pragma unroll
      for (int kt = 0; kt < 4; ++kt) {
        f16x4 bv = *(const f16x4*)&Vt[(dbase + ((kt * 4 + quad) ^ l16)) * 4];
#pragma unroll
        for (int s = 0; s < 2; ++s)
          o[s][nt] = __builtin_amdgcn_mfma_f32_16x16x16f16(pa[s][kt], bv, o[s][nt], 0, 0, 0);
      }
    }
  }

  // ---- merge the two key-half states per q-pair, then store partial
  __syncthreads();
  _Float16* Osc = (_Float16*)&Ks[0][0];   // aliased scratch [2 qp][64 lane][32]
  if (kh == 1) {
#pragma unroll
    for (int s = 0; s < 2; ++s) {
      if (quad == 0) { Msc[qp][s][l16] = m_run[s]; Lsc[qp][s][l16] = l_run[s]; }
#pragma unroll
      for (int nt = 0; nt < 4; ++nt)
#pragma unroll
        for (int g = 0; g < 4; ++g)
          Osc[(qp * 64 + lane) * 32 + s * 16 + nt * 4 + g] = (_Float16)o[s][nt][g];
    }
  }
  __syncthreads();
  if (kh == 0) {
#pragma unroll
    for (int s = 0; s < 2; ++s) {
      const float m1 = Msc[qp][s][l16];
      const float l1 = Lsc[qp][s][l16];
      const float m  = fmaxf(m_run[s], m1);
      const float a0 = __expf((m_run[s] - m) * 0.125f);
      const float a1 = __expf((m1 - m) * 0.125f);
      const float lt = l_run[s] * a0 + l1 * a1;
      const float rl = 1.f / lt;
      if (quad == 0) {                 // per-row (m,l) for cross-block merge
        int q = qbase + s * 16 + l16;
        mp[(z * NH + h) * S_LEN + q] = m;
        lp[(z * NH + h) * S_LEN + q] = lt;
      }
      float a0g[4], a1g[4], rlg[4];
#pragma unroll
      for (int g = 0; g < 4; ++g) {
        a0g[g] = __shfl(a0, quad * 4 + g);
        a1g[g] = __shfl(a1, quad * 4 + g);
        rlg[g] = __shfl(rl, quad * 4 + g);
      }
#pragma unroll
      for (int g = 0; g < 4; ++g) {
        int row = qbase + s * 16 + quad * 4 + g;
#pragma unroll
        for (int nt = 0; nt < 4; ++nt) {
          float om = o[s][nt][g] * a0g[g] + (float)Osc[(qp * 64 + lane) * 32 + s * 16 + nt * 4 + g] * a1g[g];
          float val = om * rlg[g];     // normalized partial
          if (z == 0) P0[row * DMODEL + hc + nt * 16 + l16] = val;
          else        P1[row * DMODEL + hc + nt * 16 + l16] = f2h(val);
        }
      }
    }
  }
}

// ---------------------------------------------------------------------------
// Cross-block merge of the two key-split partials: Ab = w0*P0 + w1*P1.
// grid (64, 8) block 256: thread = (row r = tid>>2, 16 d at (tid&3)*16).
// ---------------------------------------------------------------------------
__global__ __launch_bounds__(256) void merge_kernel(
    const float* __restrict__ P0, const unsigned short* __restrict__ P1,
    const float* __restrict__ mp, const float* __restrict__ lp,
    unsigned short* __restrict__ Ob)
{
  const int tid = threadIdx.x;
  const int qb = blockIdx.x, h = blockIdx.y;
  const int q = qb * 64 + (tid >> 2), hc = h * HD;
  const int dq = (tid & 3) * 16;
  const float m0 = mp[h * S_LEN + q],        l0 = lp[h * S_LEN + q];
  const float m1 = mp[(NH + h) * S_LEN + q], l1 = lp[(NH + h) * S_LEN + q];
  const float M  = fmaxf(m0, m1);
  float w0 = l0 * __expf((m0 - M) * 0.125f);
  float w1 = l1 * __expf((m1 - M) * 0.125f);
  const float rw = 1.f / (w0 + w1);
  w0 *= rw; w1 *= rw;
  const int base = q * DMODEL + hc + dq;
  f16x8 p1a = *(const f16x8*)&P1[base];
  f16x8 p1b = *(const f16x8*)&P1[base + 8];
  float4 x0 = *(const float4*)&P0[base];
  float4 x1 = *(const float4*)&P0[base + 4];
  float4 x2 = *(const float4*)&P0[base + 8];
  float4 x3 = *(const float4*)&P0[base + 12];
  f16x8 oa, ob;
  oa[0] = (_Float16)(w0 * x0.x + w1 * (float)p1a[0]);
  oa[1] = (_Float16)(w0 * x0.y + w1 * (float)p1a[1]);
  oa[2] = (_Float16)(w0 * x0.z + w1 * (float)p1a[2]);
  oa[3] = (_Float16)(w0 * x0.w + w1 * (float)p1a[3]);
  oa[4] = (_Float16)(w0 * x1.x + w1 * (float)p1a[4]);
  oa[5] = (_Float16)(w0 * x1.y + w1 * (float)p1a[5]);
  oa[6] = (_Float16)(w0 * x1.z + w1 * (float)p1a[6]);
  oa[7] = (_Float16)(w0 * x1.w + w1 * (float)p1a[7]);
  ob[0] = (_Float16)(w0 * x2.x + w1 * (float)p1b[0]);
  ob[1] = (_Float16)(w0 * x2.y + w1 * (float)p1b[1]);
  ob[2] = (_Float16)(w0 * x2.z + w1 * (float)p1b[2]);
  ob[3] = (_Float16)(w0 * x2.w + w1 * (float)p1b[3]);
  ob[4] = (_Float16)(w0 * x3.x + w1 * (float)p1b[4]);
  ob[5] = (_Float16)(w0 * x3.y + w1 * (float)p1b[5]);
  ob[6] = (_Float16)(w0 * x3.z + w1 * (float)p1b[6]);
  ob[7] = (_Float16)(w0 * x3.w + w1 * (float)p1b[7]);
  *(f16x8*)&Ob[base]     = oa;
  *(f16x8*)&Ob[base + 8] = ob;
}

// ---------------------------------------------------------------------------
extern "C" void kernel_launch(void* const* d_in, const int* in_sizes, int n_in,
                              void* d_out, int out_size, void* d_ws, size_t ws_size,
                              hipStream_t stream) {
  const float* q  = (const float*)d_in[0];
  const float* k  = (const float*)d_in[1];
  const float* v  = (const float*)d_in[2];
  const float* Wq = (const float*)d_in[3];
  const float* Wk = (const float*)d_in[4];
  const float* Wv = (const float*)d_in[5];
  const float* Wo = (const float*)d_in[6];
  const float* bo = (const float*)d_in[7];

  unsigned short* ws   = (unsigned short*)d_ws;
  unsigned short* Wqt  = ws;                  // 512*512 fp16 each
  unsigned short* Wkt  = Wqt  + 262144;
  unsigned short* Wvt  = Wkt  + 262144;
  unsigned short* Wot  = Wvt  + 262144;
  unsigned short* Wof  = Wot  + 262144;       // straight fp16 Wo
  unsigned short* Wo2t = Wof  + 262144;       // (Wo^2)^T fp16
  unsigned short* Qb   = Wo2t + 262144;       // 4096*512 fp16 each
  unsigned short* Kb   = Qb   + 2097152;
  unsigned short* VtG  = Kb   + 2097152;      // V^T [512][4096] fp16
  unsigned short* Ab   = VtG  + 2097152;      // attention output / z=1 partial
  float*          bo2  = (float*)(Ab + 2097152);  // 512 f32
  float*          mp   = bo2 + 512;           // [2][8][4096] f32 row maxes
  float*          lp   = mp + 65536;          // [2][8][4096] f32 row sums
  // high-water ~20.4 MB (ws proven >= 23 MB by rounds 1/3 equivalence)
  // z=0 partial O (f32) lives in d_out, free scratch until the final gemm.

  wtrans_kernel<<<dim3(8, 8, 4), 256, 0, stream>>>(
      Wq, Wk, Wv, Wo, Wqt, Wkt, Wvt, Wot, Wof);

  // z=0..2: Q/K/V projections (A fp32; V stored transposed);
  // z=3: Wo2t = Wot @ Wof^T (M=512) + bo2 in idle tiles
  gemm_kernel<<<dim3(64, 8, 4), 256, 0, stream>>>(
      q, k, v, Wot, Wqt, Wkt, Wvt, Wof, Qb, Kb, nullptr, Wo2t,
      nullptr, VtG, Wo, bo, bo2, 0x7, 0x0);

  attn_kernel<<<dim3(64, 8, 2), 256, 0, stream>>>(
      Qb, Kb, VtG, (float*)d_out, Ab, mp, lp);

  merge_kernel<<<dim3(64, 8), 256, 0, stream>>>(
      (const float*)d_out, Ab, mp, lp, Ab);

  // single fused fc_out: d_out = Ab @ Wo2 + bo2   (fp32 out)
  gemm_kernel<<<dim3(64, 8, 1), 256, 0, stream>>>(
      Ab, nullptr, nullptr, nullptr, Wo2t, nullptr, nullptr, nullptr,
      d_out, nullptr, nullptr, nullptr, bo2, nullptr,
      nullptr, nullptr, nullptr, 0x0, 0x1);
}

// Round 4
// 212.876 us; speedup vs baseline: 1.8350x; 1.0033x over previous
//
#include <hip/hip_runtime.h>

#define S_LEN  4096
#define DMODEL 512
#define NH     8
#define HD     64

typedef _Float16 f16x8 __attribute__((ext_vector_type(8)));
typedef _Float16 f16x4 __attribute__((ext_vector_type(4)));
typedef float    f32x4 __attribute__((ext_vector_type(4)));

static __device__ __forceinline__ unsigned short f2h(float x) {
  return __builtin_bit_cast(unsigned short, (_Float16)x);
}

// ---------------------------------------------------------------------------
// Weight transpose + fp32->fp16: Wt[n][k] = (fp16) W[k][n].  For z==3 (Wo)
// also emits the straight fp16 copy Wof[k][n].  grid (8,8,4) block 256
// ---------------------------------------------------------------------------
__global__ __launch_bounds__(256) void wtrans_kernel(
    const float* __restrict__ w0, const float* __restrict__ w1,
    const float* __restrict__ w2, const float* __restrict__ w3,
    unsigned short* __restrict__ o0, unsigned short* __restrict__ o1,
    unsigned short* __restrict__ o2, unsigned short* __restrict__ o3,
    unsigned short* __restrict__ o3s)
{
  __shared__ unsigned short T[64 * 72];   // T[n_local][k_local], pad 72
  const float* W; unsigned short* O;
  switch (blockIdx.z) {
    case 0:  W = w0; O = o0; break;
    case 1:  W = w1; O = o1; break;
    case 2:  W = w2; O = o2; break;
    default: W = w3; O = o3; break;
  }
  const int tid = threadIdx.x;
  const int k0 = blockIdx.x * 64, n0 = blockIdx.y * 64;
  const int c4 = (tid & 15) * 4;
#pragma unroll
  for (int rp = 0; rp < 4; ++rp) {
    int r = rp * 16 + (tid >> 4);
    float4 x = *(const float4*)(W + (k0 + r) * DMODEL + n0 + c4);
    T[(c4 + 0) * 72 + r] = f2h(x.x);
    T[(c4 + 1) * 72 + r] = f2h(x.y);
    T[(c4 + 2) * 72 + r] = f2h(x.z);
    T[(c4 + 3) * 72 + r] = f2h(x.w);
    if (blockIdx.z == 3) {
      f16x4 st;
      st[0] = (_Float16)x.x; st[1] = (_Float16)x.y;
      st[2] = (_Float16)x.z; st[3] = (_Float16)x.w;
      *(f16x4*)&o3s[(k0 + r) * DMODEL + n0 + c4] = st;
    }
  }
  __syncthreads();
#pragma unroll
  for (int it = 0; it < 2; ++it) {
    int i = tid + it * 256;
    int nl = i >> 3, c = i & 7;
    *(f16x8*)&O[(n0 + nl) * DMODEL + k0 + c * 8] = *(const f16x8*)&T[nl * 72 + c * 8];
  }
}

// ---------------------------------------------------------------------------
// 128x128-tile GEMM (multi-op), BK=32, 4 waves each computing 64x64 via
// 4x4 16x16x32 fragments (16 MFMAs per barrier-pair vs 4 in the old 64-tile
// body -- the old kernel exposed ~700cy global latency every k-step).
// Register-prefetch staging (attn-proven): next k-step's global loads are
// issued into regs during compute, written to LDS after the barrier.
// Fragment math identical to the round-2-proven 64x64 body (same K-chunk
// order -> bitwise-identical outputs).
// blockIdx.z selects op; z==3: x<4 -> Wo2t 128-tiles (M=512), x in 4..11 &
// y==0 -> bo2 side-job. vtg!=null && z==2: C stored transposed (V^T).
// grid (32,4,nz) block 256.
// ---------------------------------------------------------------------------
__global__ __launch_bounds__(256) void gemm128_kernel(
    const void* __restrict__ A0, const void* __restrict__ A1,
    const void* __restrict__ A2, const void* __restrict__ A3,
    const unsigned short* __restrict__ B0, const unsigned short* __restrict__ B1,
    const unsigned short* __restrict__ B2, const unsigned short* __restrict__ B3,
    void* __restrict__ C0, void* __restrict__ C1,
    void* __restrict__ C2, void* __restrict__ C3,
    const float* __restrict__ bias, unsigned short* __restrict__ vtg,
    const float* __restrict__ wo_f32, const float* __restrict__ bo_in,
    float* __restrict__ bo2_out,
    int a_fp32_mask, int c_fp32_mask)
{
  constexpr int K = DMODEL, N = DMODEL;
  __shared__ unsigned short As[128 * 32];
  __shared__ unsigned short Bs[128 * 32];
  const int z = blockIdx.z;
  if (z == 3 && blockIdx.x >= 4) {          // idle tiles: bo2 side-job
    if (blockIdx.x < 12 && blockIdx.y == 0 && wo_f32) {
      int col = (blockIdx.x - 4) * 64 + (threadIdx.x & 63);
      float s = bo_in[col];
#pragma unroll 8
      for (int j = 0; j < DMODEL; ++j) s = fmaf(bo_in[j], wo_f32[j * DMODEL + col], s);
      bo2_out[col] = s;
    }
    return;
  }
  const void* Av; const unsigned short* Bt; void* Cv;
  switch (z) {
    case 0:  Av = A0; Bt = B0; Cv = C0; break;
    case 1:  Av = A1; Bt = B1; Cv = C1; break;
    case 2:  Av = A2; Bt = B2; Cv = C2; break;
    default: Av = A3; Bt = B3; Cv = C3; break;
  }
  const int a_fp32 = (a_fp32_mask >> z) & 1;
  const int c_fp32 = (c_fp32_mask >> z) & 1;
  const int tid  = threadIdx.x;
  const int lane = tid & 63;
  const int wid  = tid >> 6;
  const int quad = lane >> 4, l16 = lane & 15;
  const int m0 = blockIdx.x * 128, n0 = blockIdx.y * 128;
  const int wm = (wid >> 1) * 64, wn = (wid & 1) * 64;
  f32x4 acc[4][4] = {};

  // staging decomposition: it in 0..1: s = it*256+tid; r = s>>2; ck = (s&3)*8
  // (exact 2x tiling of the proven conflict-free 64-tile staging)
  f16x8 areg[2], breg[2];
#pragma unroll
  for (int it = 0; it < 2; ++it) {      // prefetch k0 = 0
    int s = it * 256 + tid;
    int r = s >> 2, ck = (s & 3) * 8;
    if (a_fp32) {
      const float* p = (const float*)Av + (m0 + r) * K + ck;
      float4 x = *(const float4*)p;
      float4 y = *(const float4*)(p + 4);
      f16x8 av;
      av[0] = (_Float16)x.x; av[1] = (_Float16)x.y;
      av[2] = (_Float16)x.z; av[3] = (_Float16)x.w;
      av[4] = (_Float16)y.x; av[5] = (_Float16)y.y;
      av[6] = (_Float16)y.z; av[7] = (_Float16)y.w;
      areg[it] = av;
    } else {
      areg[it] = *(const f16x8*)((const unsigned short*)Av + (m0 + r) * K + ck);
    }
    breg[it] = *(const f16x8*)(Bt + (n0 + r) * K + ck);
  }

  for (int k0 = 0; k0 < K; k0 += 32) {
    __syncthreads();
#pragma unroll
    for (int it = 0; it < 2; ++it) {
      int s = it * 256 + tid;
      int r = s >> 2, ck = (s & 3) * 8;
      *(f16x8*)&As[r * 32 + ck] = areg[it];
      *(f16x8*)&Bs[r * 32 + ck] = breg[it];
    }
    __syncthreads();

    if (k0 + 32 < K) {                  // prefetch next k-step into registers
      int kk = k0 + 32;
#pragma unroll
      for (int it = 0; it < 2; ++it) {
        int s = it * 256 + tid;
        int r = s >> 2, ck = (s & 3) * 8;
        if (a_fp32) {
          const float* p = (const float*)Av + (m0 + r) * K + kk + ck;
          float4 x = *(const float4*)p;
          float4 y = *(const float4*)(p + 4);
          f16x8 av;
          av[0] = (_Float16)x.x; av[1] = (_Float16)x.y;
          av[2] = (_Float16)x.z; av[3] = (_Float16)x.w;
          av[4] = (_Float16)y.x; av[5] = (_Float16)y.y;
          av[6] = (_Float16)y.z; av[7] = (_Float16)y.w;
          areg[it] = av;
        } else {
          areg[it] = *(const f16x8*)((const unsigned short*)Av + (m0 + r) * K + kk + ck);
        }
        breg[it] = *(const f16x8*)(Bt + (n0 + r) * K + kk + ck);
      }
    }

    f16x8 af[4], bf[4];
#pragma unroll
    for (int mt = 0; mt < 4; ++mt)
      af[mt] = *(const f16x8*)&As[(wm + mt * 16 + l16) * 32 + quad * 8];
#pragma unroll
    for (int nt = 0; nt < 4; ++nt)
      bf[nt] = *(const f16x8*)&Bs[(wn + nt * 16 + l16) * 32 + quad * 8];
#pragma unroll
    for (int mt = 0; mt < 4; ++mt)
#pragma unroll
      for (int nt = 0; nt < 4; ++nt)
        acc[mt][nt] = __builtin_amdgcn_mfma_f32_16x16x32_f16(af[mt], bf[nt], acc[mt][nt], 0, 0, 0);
  }

  const int do_vt = (vtg != nullptr) && (z == 2);
#pragma unroll
  for (int mt = 0; mt < 4; ++mt)
#pragma unroll
    for (int nt = 0; nt < 4; ++nt) {
      int col = n0 + wn + nt * 16 + l16;
      float bv = bias ? bias[col] : 0.f;
#pragma unroll
      for (int g = 0; g < 4; ++g) {
        int row = m0 + wm + mt * 16 + quad * 4 + g;   // C/D: row = quad*4+reg
        float val = acc[mt][nt][g] + bv;
        if (do_vt)        vtg[col * S_LEN + row] = f2h(val);      // V^T[d][key]
        else if (c_fp32)  ((float*)Cv)[row * N + col] = val;
        else              ((unsigned short*)Cv)[row * N + col] = f2h(val);
      }
    }
}

// ---------------------------------------------------------------------------
// Split-K MFMA flash attention, S^T formulation, 2 q-sets per wave,
// register-prefetched staging. Round-0 proven 256-thread body (VGPR 112,
// no spill), key-split ACROSS blocks: grid (64, 8, 2) = 1024 blocks,
// z handles keys [z*2048, z*2048+2048) as 2 kh-halves of 1024 (16 iters).
// LDS 35.3 KB: Vt XOR-swizzled stride-64 (conflict-free ds_read_b64 in PV),
// merge scratch aliased on Ks. Partials: z=0 -> f32 in d_out (scratch until
// final gemm), z=1 -> fp16 in Ab; per-row (m,l) to ws. merge_kernel combines.
// NOTE rounds 0-3: time is invariant to grid/occupancy knobs (93-95us at
// "2 blocks/CU" and "4 blocks/CU" alike); frozen this round.
// ---------------------------------------------------------------------------
__global__ __launch_bounds__(256) void attn_kernel(
    const unsigned short* __restrict__ Qb, const unsigned short* __restrict__ Kb,
    const unsigned short* __restrict__ VtG,
    float* __restrict__ P0, unsigned short* __restrict__ P1,
    float* __restrict__ mp, float* __restrict__ lp)
{
  __shared__ unsigned short Ks[2][64 * 72];   // K[n][k] per half, pad 72
  __shared__ unsigned short Vt[2 * 64 * 64];  // V^T swizzled, stride 64, no pad
  __shared__ float Msc[2][2][16];             // merge scratch m [qp][s][l16]
  __shared__ float Lsc[2][2][16];             // merge scratch l

  const int tid  = threadIdx.x;
  const int lane = tid & 63;
  const int wid  = tid >> 6;        // 0..3
  const int qp   = wid & 1;         // q-pair (32 q-rows)
  const int kh   = wid >> 1;        // 1024-key half within this z-chunk
  const int quad = lane >> 4, l16 = lane & 15;
  const int qb = blockIdx.x, h = blockIdx.y, z = blockIdx.z;
  const int hc = h * HD;
  const int qbase = qb * 64 + qp * 32;
  const int kz = z * 2048;

  // Persistent Q fragments (B operand), 2 sets: Q[q=l16][d=quad*8+j (+32)]
  f16x8 bq[2][2];
#pragma unroll
  for (int s = 0; s < 2; ++s) {
    int qrow = qbase + s * 16 + l16;
    bq[s][0] = *(const f16x8*)(Qb + qrow * DMODEL + hc + quad * 8);
    bq[s][1] = *(const f16x8*)(Qb + qrow * DMODEL + hc + 32 + quad * 8);
  }

  // o[s][nt] holds O[q = quad*4+g][d = nt*16 + l16] for set s
  f32x4 o[2][4] = {};
  float m_run[2] = {-1e30f, -1e30f}, l_run[2] = {0.f, 0.f};

  // staging decomposition (256 threads, 1024 chunks per array):
  // it in 0..3: s = it*256+tid; khs = s>>9; n = (s>>3)&63; c = s&7
  f16x8 kreg[4], vreg[4];
#pragma unroll
  for (int it = 0; it < 4; ++it) {     // prefetch kbi = 0
    int s = it * 256 + tid;
    int khs = s >> 9, n = (s >> 3) & 63, c = s & 7;
    kreg[it] = *(const f16x8*)(Kb + (kz + khs * 1024 + n) * DMODEL + hc + c * 8);
    vreg[it] = *(const f16x8*)(VtG + (hc + n) * S_LEN + kz + khs * 1024 + c * 8);
  }

  for (int kbi = 0; kbi < 16; ++kbi) {
    __syncthreads();                   // all waves done reading previous tiles
#pragma unroll
    for (int it = 0; it < 4; ++it) {
      int s = it * 256 + tid;
      int khs = s >> 9, n = (s >> 3) & 63, c = s & 7;
      *(f16x8*)&Ks[khs][n * 72 + c * 8] = kreg[it];
      // swizzled Vt: granule (2c+j) of row d=n at u=(khs*64+n)*16+((2c+j)^(n&15))
      int vbase = (khs * 64 + n) * 16;
      int n15 = n & 15;
      f16x4 lo = __builtin_shufflevector(vreg[it], vreg[it], 0, 1, 2, 3);
      f16x4 hi = __builtin_shufflevector(vreg[it], vreg[it], 4, 5, 6, 7);
      *(f16x4*)&Vt[(vbase + ((2 * c) ^ n15)) * 4]     = lo;
      *(f16x4*)&Vt[(vbase + ((2 * c + 1) ^ n15)) * 4] = hi;
    }
    __syncthreads();                   // staging visible

    if (kbi + 1 < 16) {                // prefetch next chunk into registers
      int kb1 = (kbi + 1) * 64;
#pragma unroll
      for (int it = 0; it < 4; ++it) {
        int s = it * 256 + tid;
        int khs = s >> 9, n = (s >> 3) & 63, c = s & 7;
        kreg[it] = *(const f16x8*)(Kb + (kz + khs * 1024 + kb1 + n) * DMODEL + hc + c * 8);
        vreg[it] = *(const f16x8*)(VtG + (hc + n) * S_LEN + kz + khs * 1024 + kb1 + c * 8);
      }
    }

    // ---- S^T = K Q^T : one Ks read feeds both q-sets
    f32x4 sT[2][4];
#pragma unroll
    for (int kt = 0; kt < 4; ++kt) {
      f16x8 ak0 = *(const f16x8*)&Ks[kh][(kt * 16 + l16) * 72 + quad * 8];
      f16x8 ak1 = *(const f16x8*)&Ks[kh][(kt * 16 + l16) * 72 + 32 + quad * 8];
#pragma unroll
      for (int s = 0; s < 2; ++s) {
        f32x4 a = {};
        a = __builtin_amdgcn_mfma_f32_16x16x32_f16(ak0, bq[s][0], a, 0, 0, 0);
        a = __builtin_amdgcn_mfma_f32_16x16x32_f16(ak1, bq[s][1], a, 0, 0, 0);
        sT[s][kt] = a;
      }
    }

    // ---- online softmax per set (scale 1/8 folded into exp), defer-max
    f16x4 pa[2][4];
#pragma unroll
    for (int s = 0; s < 2; ++s) {
      float vmax = -1e30f;
#pragma unroll
      for (int kt = 0; kt < 4; ++kt)
#pragma unroll
        for (int g = 0; g < 4; ++g) vmax = fmaxf(vmax, sT[s][kt][g]);
      vmax = fmaxf(vmax, __shfl_xor(vmax, 16));
      vmax = fmaxf(vmax, __shfl_xor(vmax, 32));

      if (__all(vmax <= m_run[s] + 8.0f)) {
        // deferred: keep old max, no rescale; p bounded by e^1
        const float mn = m_run[s];
        float rs = 0.f;
#pragma unroll
        for (int kt = 0; kt < 4; ++kt)
#pragma unroll
          for (int g = 0; g < 4; ++g) {
            float p = __expf((sT[s][kt][g] - mn) * 0.125f);
            rs += p;
            pa[s][kt][g] = (_Float16)p;
          }
        rs += __shfl_xor(rs, 16);
        rs += __shfl_xor(rs, 32);
        l_run[s] += rs;
      } else {
        const float mn = fmaxf(m_run[s], vmax);
        const float alpha = __expf((m_run[s] - mn) * 0.125f);
        m_run[s] = mn;

        float rs = 0.f;
#pragma unroll
        for (int kt = 0; kt < 4; ++kt)
#pragma unroll
          for (int g = 0; g < 4; ++g) {
            float p = __expf((sT[s][kt][g] - mn) * 0.125f);
            rs += p;
            pa[s][kt][g] = (_Float16)p;
          }
        rs += __shfl_xor(rs, 16);
        rs += __shfl_xor(rs, 32);
        l_run[s] = l_run[s] * alpha + rs;

        float ag[4];
#pragma unroll
        for (int g = 0; g < 4; ++g) ag[g] = __shfl(alpha, quad * 4 + g);
#pragma unroll
        for (int nt = 0; nt < 4; ++nt)
#pragma unroll
          for (int g = 0; g < 4; ++g) o[s][nt][g] *= ag[g];
      }
    }

    // ---- O += P @ V : swizzled conflict-free Vt b64 reads feed both q-sets
#pragma unroll
    for (int nt = 0; nt < 4; ++nt) {
      int dbase = (kh * 64 + nt * 16 + l16) * 16;
#pragma unroll
      for (int kt = 0; kt < 4; ++kt) {
        f16x4 bv = *(const f16x4*)&Vt[(dbase + ((kt * 4 + quad) ^ l16)) * 4];
#pragma unroll
        for (int s = 0; s < 2; ++s)
          o[s][nt] = __builtin_amdgcn_mfma_f32_16x16x16f16(pa[s][kt], bv, o[s][nt], 0, 0, 0);
      }
    }
  }

  // ---- merge the two key-half states per q-pair, then store partial
  __syncthreads();
  _Float16* Osc = (_Float16*)&Ks[0][0];   // aliased scratch [2 qp][64 lane][32]
  if (kh == 1) {
#pragma unroll
    for (int s = 0; s < 2; ++s) {
      if (quad == 0) { Msc[qp][s][l16] = m_run[s]; Lsc[qp][s][l16] = l_run[s]; }
#pragma unroll
      for (int nt = 0; nt < 4; ++nt)
#pragma unroll
        for (int g = 0; g < 4; ++g)
          Osc[(qp * 64 + lane) * 32 + s * 16 + nt * 4 + g] = (_Float16)o[s][nt][g];
    }
  }
  __syncthreads();
  if (kh == 0) {
#pragma unroll
    for (int s = 0; s < 2; ++s) {
      const float m1 = Msc[qp][s][l16];
      const float l1 = Lsc[qp][s][l16];
      const float m  = fmaxf(m_run[s], m1);
      const float a0 = __expf((m_run[s] - m) * 0.125f);
      const float a1 = __expf((m1 - m) * 0.125f);
      const float lt = l_run[s] * a0 + l1 * a1;
      const float rl = 1.f / lt;
      if (quad == 0) {                 // per-row (m,l) for cross-block merge
        int q = qbase + s * 16 + l16;
        mp[(z * NH + h) * S_LEN + q] = m;
        lp[(z * NH + h) * S_LEN + q] = lt;
      }
      float a0g[4], a1g[4], rlg[4];
#pragma unroll
      for (int g = 0; g < 4; ++g) {
        a0g[g] = __shfl(a0, quad * 4 + g);
        a1g[g] = __shfl(a1, quad * 4 + g);
        rlg[g] = __shfl(rl, quad * 4 + g);
      }
#pragma unroll
      for (int g = 0; g < 4; ++g) {
        int row = qbase + s * 16 + quad * 4 + g;
#pragma unroll
        for (int nt = 0; nt < 4; ++nt) {
          float om = o[s][nt][g] * a0g[g] + (float)Osc[(qp * 64 + lane) * 32 + s * 16 + nt * 4 + g] * a1g[g];
          float val = om * rlg[g];     // normalized partial
          if (z == 0) P0[row * DMODEL + hc + nt * 16 + l16] = val;
          else        P1[row * DMODEL + hc + nt * 16 + l16] = f2h(val);
        }
      }
    }
  }
}

// ---------------------------------------------------------------------------
// Cross-block merge of the two key-split partials: Ab = w0*P0 + w1*P1.
// grid (64, 8) block 256: thread = (row r = tid>>2, 16 d at (tid&3)*16).
// ---------------------------------------------------------------------------
__global__ __launch_bounds__(256) void merge_kernel(
    const float* __restrict__ P0, const unsigned short* __restrict__ P1,
    const float* __restrict__ mp, const float* __restrict__ lp,
    unsigned short* __restrict__ Ob)
{
  const int tid = threadIdx.x;
  const int qb = blockIdx.x, h = blockIdx.y;
  const int q = qb * 64 + (tid >> 2), hc = h * HD;
  const int dq = (tid & 3) * 16;
  const float m0 = mp[h * S_LEN + q],        l0 = lp[h * S_LEN + q];
  const float m1 = mp[(NH + h) * S_LEN + q], l1 = lp[(NH + h) * S_LEN + q];
  const float M  = fmaxf(m0, m1);
  float w0 = l0 * __expf((m0 - M) * 0.125f);
  float w1 = l1 * __expf((m1 - M) * 0.125f);
  const float rw = 1.f / (w0 + w1);
  w0 *= rw; w1 *= rw;
  const int base = q * DMODEL + hc + dq;
  f16x8 p1a = *(const f16x8*)&P1[base];
  f16x8 p1b = *(const f16x8*)&P1[base + 8];
  float4 x0 = *(const float4*)&P0[base];
  float4 x1 = *(const float4*)&P0[base + 4];
  float4 x2 = *(const float4*)&P0[base + 8];
  float4 x3 = *(const float4*)&P0[base + 12];
  f16x8 oa, ob;
  oa[0] = (_Float16)(w0 * x0.x + w1 * (float)p1a[0]);
  oa[1] = (_Float16)(w0 * x0.y + w1 * (float)p1a[1]);
  oa[2] = (_Float16)(w0 * x0.z + w1 * (float)p1a[2]);
  oa[3] = (_Float16)(w0 * x0.w + w1 * (float)p1a[3]);
  oa[4] = (_Float16)(w0 * x1.x + w1 * (float)p1a[4]);
  oa[5] = (_Float16)(w0 * x1.y + w1 * (float)p1a[5]);
  oa[6] = (_Float16)(w0 * x1.z + w1 * (float)p1a[6]);
  oa[7] = (_Float16)(w0 * x1.w + w1 * (float)p1a[7]);
  ob[0] = (_Float16)(w0 * x2.x + w1 * (float)p1b[0]);
  ob[1] = (_Float16)(w0 * x2.y + w1 * (float)p1b[1]);
  ob[2] = (_Float16)(w0 * x2.z + w1 * (float)p1b[2]);
  ob[3] = (_Float16)(w0 * x2.w + w1 * (float)p1b[3]);
  ob[4] = (_Float16)(w0 * x3.x + w1 * (float)p1b[4]);
  ob[5] = (_Float16)(w0 * x3.y + w1 * (float)p1b[5]);
  ob[6] = (_Float16)(w0 * x3.z + w1 * (float)p1b[6]);
  ob[7] = (_Float16)(w0 * x3.w + w1 * (float)p1b[7]);
  *(f16x8*)&Ob[base]     = oa;
  *(f16x8*)&Ob[base + 8] = ob;
}

// ---------------------------------------------------------------------------
extern "C" void kernel_launch(void* const* d_in, const int* in_sizes, int n_in,
                              void* d_out, int out_size, void* d_ws, size_t ws_size,
                              hipStream_t stream) {
  const float* q  = (const float*)d_in[0];
  const float* k  = (const float*)d_in[1];
  const float* v  = (const float*)d_in[2];
  const float* Wq = (const float*)d_in[3];
  const float* Wk = (const float*)d_in[4];
  const float* Wv = (const float*)d_in[5];
  const float* Wo = (const float*)d_in[6];
  const float* bo = (const float*)d_in[7];

  unsigned short* ws   = (unsigned short*)d_ws;
  unsigned short* Wqt  = ws;                  // 512*512 fp16 each
  unsigned short* Wkt  = Wqt  + 262144;
  unsigned short* Wvt  = Wkt  + 262144;
  unsigned short* Wot  = Wvt  + 262144;
  unsigned short* Wof  = Wot  + 262144;       // straight fp16 Wo
  unsigned short* Wo2t = Wof  + 262144;       // (Wo^2)^T fp16
  unsigned short* Qb   = Wo2t + 262144;       // 4096*512 fp16 each
  unsigned short* Kb   = Qb   + 2097152;
  unsigned short* VtG  = Kb   + 2097152;      // V^T [512][4096] fp16
  unsigned short* Ab   = VtG  + 2097152;      // attention output / z=1 partial
  float*          bo2  = (float*)(Ab + 2097152);  // 512 f32
  float*          mp   = bo2 + 512;           // [2][8][4096] f32 row maxes
  float*          lp   = mp + 65536;          // [2][8][4096] f32 row sums
  // high-water ~20.4 MB (ws proven >= 23 MB)
  // z=0 partial O (f32) lives in d_out, free scratch until the final gemm.

  wtrans_kernel<<<dim3(8, 8, 4), 256, 0, stream>>>(
      Wq, Wk, Wv, Wo, Wqt, Wkt, Wvt, Wot, Wof);

  // z=0..2: Q/K/V projections (A fp32; V stored transposed);
  // z=3: Wo2t = Wot @ Wof^T (M=512, x<4) + bo2 in idle tiles (x 4..11, y 0)
  gemm128_kernel<<<dim3(32, 4, 4), 256, 0, stream>>>(
      q, k, v, Wot, Wqt, Wkt, Wvt, Wof, Qb, Kb, nullptr, Wo2t,
      nullptr, VtG, Wo, bo, bo2, 0x7, 0x0);

  attn_kernel<<<dim3(64, 8, 2), 256, 0, stream>>>(
      Qb, Kb, VtG, (float*)d_out, Ab, mp, lp);

  merge_kernel<<<dim3(64, 8), 256, 0, stream>>>(
      (const float*)d_out, Ab, mp, lp, Ab);

  // single fused fc_out: d_out = Ab @ Wo2 + bo2   (fp32 out)
  gemm128_kernel<<<dim3(32, 4, 1), 256, 0, stream>>>(
      Ab, nullptr, nullptr, nullptr, Wo2t, nullptr, nullptr, nullptr,
      d_out, nullptr, nullptr, nullptr, bo2, nullptr,
      nullptr, nullptr, nullptr, 0x0, 0x1);
}